// Round 11
// baseline (278.337 us; speedup 1.0000x reference)
//
#include <hip/hip_runtime.h>
#include <math.h>

#define S_LEN 2048
#define DMODEL 1024
#define NHEAD 16
#define HD 64
#define NBATCH 2

using short8  = __attribute__((ext_vector_type(8))) short;
using ushort8 = __attribute__((ext_vector_type(8))) unsigned short;
using floatx4 = __attribute__((ext_vector_type(4))) float;
using uint4v  = __attribute__((ext_vector_type(4))) unsigned int;

__device__ __forceinline__ unsigned short f2b(float f) {
    unsigned int u = __float_as_uint(f);
    unsigned int r = (u + 0x7FFFu + ((u >> 16) & 1u)) >> 16;
    return (unsigned short)r;
}
__device__ __forceinline__ float b2f(unsigned short b) {
    return __uint_as_float(((unsigned int)b) << 16);
}

// pack two fp32 -> one u32 of 2 bf16 (round-half-up): 2 adds + 1 v_perm
__device__ __forceinline__ unsigned int pkbf(float a, float b) {
    unsigned int ua = __float_as_uint(a) + 0x8000u;
    unsigned int ub = __float_as_uint(b) + 0x8000u;
    return __builtin_amdgcn_perm(ub, ua, 0x07060302u);  // [ua.b2,ua.b3,ub.b2,ub.b3]
}

// async global->LDS, 16B per lane; LDS dest = wave-uniform base + lane*16
__device__ __forceinline__ void gll16(const void* g, void* l) {
    __builtin_amdgcn_global_load_lds(
        (const __attribute__((address_space(1))) unsigned int*)g,
        (__attribute__((address_space(3))) unsigned int*)l, 16, 0, 0);
}

// ---------------------------------------------------------------------------
__global__ __launch_bounds__(256)
void transpose_w(const float* __restrict__ W0, const float* __restrict__ W1,
                 const float* __restrict__ W2, const float* __restrict__ W3,
                 unsigned short* __restrict__ T0, unsigned short* __restrict__ T1,
                 unsigned short* __restrict__ T2, unsigned short* __restrict__ T3)
{
    __shared__ float t[64][65];
    const float* W; unsigned short* T;
    switch (blockIdx.z) {
        case 0: W = W0; T = T0; break;
        case 1: W = W1; T = T1; break;
        case 2: W = W2; T = T2; break;
        default: W = W3; T = T3; break;
    }
    const int tid = threadIdx.x;
    const int c0 = blockIdx.x * 64;
    const int r0 = blockIdx.y * 64;
    #pragma unroll
    for (int i = 0; i < 4; ++i) {
        int c = tid + i * 256;
        int r = c >> 4, off = (c & 15) * 4;
        float4 v = *(const float4*)(W + (size_t)(r0 + r) * DMODEL + c0 + off);
        t[r][off + 0] = v.x; t[r][off + 1] = v.y;
        t[r][off + 2] = v.z; t[r][off + 3] = v.w;
    }
    __syncthreads();
    #pragma unroll
    for (int i = 0; i < 4; ++i) {
        int c = tid + i * 256;
        int n = c >> 4, off = (c & 15) * 4;
        ushort4 o;
        o.x = f2b(t[off + 0][n]); o.y = f2b(t[off + 1][n]);
        o.z = f2b(t[off + 2][n]); o.w = f2b(t[off + 3][n]);
        *(ushort4*)(T + (size_t)(c0 + n) * DMODEL + r0 + off) = o;
    }
}

// ---------------------------------------------------------------------------
// QKV GEMM with fused fp32->bf16: X staged as fp32 via global_load_lds
// (async path preserved — the R8 regression was reg-staged scalar ds_writes),
// converted to bf16 in-register AFTER the LDS read, in A-frag prep.
// 16B-granule XOR swizzle: slot s of row r holds logical granule s^(r&7);
// frag halves read at (2lb)^(r&7) and (2lb+1)^(r&7) -> 8 slots, 2-way banks.
// W path unchanged (bf16 gll16). Tile 128x128, BK=64, LDS 48KB (3 blk/CU).
// ---------------------------------------------------------------------------
__global__ __launch_bounds__(256)
void gemm_qkv(const float* __restrict__ X0, const float* __restrict__ X1,
              const float* __restrict__ X2,
              const unsigned short* __restrict__ W0, const unsigned short* __restrict__ W1,
              const unsigned short* __restrict__ W2,
              const float* __restrict__ b0, const float* __restrict__ b1,
              const float* __restrict__ b2,
              unsigned short* __restrict__ o0, unsigned short* __restrict__ o1,
              unsigned short* __restrict__ o2)
{
    __shared__ float Xs[128 * 64];           // fp32, 32 KB
    __shared__ unsigned short Ws[128 * 64];  // bf16, 16 KB

    const float* X           = (blockIdx.z == 0) ? X0 : (blockIdx.z == 1) ? X1 : X2;
    const unsigned short* Wt = (blockIdx.z == 0) ? W0 : (blockIdx.z == 1) ? W1 : W2;
    const float* bias        = (blockIdx.z == 0) ? b0 : (blockIdx.z == 1) ? b1 : b2;
    unsigned short* outp     = (blockIdx.z == 0) ? o0 : (blockIdx.z == 1) ? o1 : o2;

    const int tid = threadIdx.x;
    const int lane = tid & 63, w = tid >> 6;
    const int l15 = lane & 15, l4 = lane >> 4;
    const int wr = w >> 1, wc = w & 1;
    const int row0 = blockIdx.y * 128;
    const int col0 = blockIdx.x * 128;

    // W staging (bf16, rows of 128B, 8 granules): as before
    const int srow = lane >> 3;
    const int sblk = (lane & 7) ^ srow;

    // X staging (fp32, rows of 256B, 16 granules): 4 rows per gll16 inst
    const int xr = lane >> 4;               // row within 4-row group
    const int xs = lane & 15;               // 16B slot in row

    floatx4 acc[4][4] = {};

    for (int k0 = 0; k0 < DMODEL; k0 += 64) {
        __syncthreads();
        #pragma unroll
        for (int i = 0; i < 8; ++i) {       // X: 32 rows/wave, fp32
            const int r = w * 32 + i * 4 + xr;
            gll16(X + (size_t)(row0 + r) * DMODEL + k0 + ((xs ^ (r & 7)) << 2),
                  &Xs[(w * 32 + i * 4) * 64]);
        }
        #pragma unroll
        for (int i = 0; i < 4; ++i)         // W: bf16
            gll16(Wt + (size_t)(col0 + w * 32 + i * 8 + srow) * DMODEL + k0 + sblk * 8,
                  &Ws[(w * 32 + i * 8) * 64]);
        asm volatile("s_waitcnt vmcnt(0)" ::: "memory");
        __syncthreads();

        #pragma unroll
        for (int ks = 0; ks < 2; ++ks) {
            short8 a[4], b[4];
            #pragma unroll
            for (int m = 0; m < 4; ++m) {
                const int r = wr * 64 + m * 16 + l15;
                const int g0 = ((ks * 4 + l4) * 2) ^ (r & 7);   // logical granule 2lb
                const floatx4 lo = *(const floatx4*)&Xs[r * 64 + g0 * 4];
                const floatx4 hi = *(const floatx4*)&Xs[r * 64 + (g0 ^ 1) * 4];
                union { uint4v u; short8 s; } cv;
                cv.u[0] = pkbf(lo[0], lo[1]);
                cv.u[1] = pkbf(lo[2], lo[3]);
                cv.u[2] = pkbf(hi[0], hi[1]);
                cv.u[3] = pkbf(hi[2], hi[3]);
                a[m] = cv.s;
            }
            #pragma unroll
            for (int n = 0; n < 4; ++n) {
                const int r = wc * 64 + n * 16 + l15;
                b[n] = *(const short8*)&Ws[r * 64 + (((ks * 4 + l4) ^ (r & 7)) << 3)];
            }
            #pragma unroll
            for (int m = 0; m < 4; ++m)
                #pragma unroll
                for (int n = 0; n < 4; ++n)
                    acc[m][n] = __builtin_amdgcn_mfma_f32_16x16x32_bf16(
                        a[m], b[n], acc[m][n], 0, 0, 0);
        }
    }

    float bl[4];
    #pragma unroll
    for (int n = 0; n < 4; ++n)
        bl[n] = bias[col0 + wc * 64 + n * 16 + l15];

    #pragma unroll
    for (int m = 0; m < 4; ++m)
        #pragma unroll
        for (int n = 0; n < 4; ++n) {
            const int gc = col0 + wc * 64 + n * 16 + l15;
            const int h = gc >> 6, d = gc & 63;
            #pragma unroll
            for (int reg = 0; reg < 4; ++reg) {
                const int gr = row0 + wr * 64 + m * 16 + l4 * 4 + reg;
                const int bb = gr >> 11, s = gr & 2047;
                outp[(((size_t)bb * NHEAD + h) * S_LEN + s) * HD + d] =
                    f2b(acc[m][n][reg] + bl[n]);
            }
        }
}

// ---------------------------------------------------------------------------
// Output projection GEMM, tile 128x64 -> grid (16,32)=512 wg = 2 blocks/CU.
// ---------------------------------------------------------------------------
__global__ __launch_bounds__(256)
void gemm_out(const unsigned short* __restrict__ X, const unsigned short* __restrict__ Wt,
              const float* __restrict__ bias, float* __restrict__ out)
{
    __shared__ unsigned short Xs[128 * 64];
    __shared__ unsigned short Ws[64 * 64];

    const int tid = threadIdx.x;
    const int lane = tid & 63, w = tid >> 6;
    const int l15 = lane & 15, l4 = lane >> 4;
    const int wr = w >> 1, wc = w & 1;
    const int row0 = blockIdx.y * 128;
    const int col0 = blockIdx.x * 64;

    const int srow = lane >> 3;
    const int sblk = (lane & 7) ^ srow;

    floatx4 acc[4][2] = {};

    for (int k0 = 0; k0 < DMODEL; k0 += 64) {
        __syncthreads();
        #pragma unroll
        for (int i = 0; i < 4; ++i)
            gll16(X + (size_t)(row0 + w * 32 + i * 8 + srow) * DMODEL + k0 + sblk * 8,
                  &Xs[(w * 32 + i * 8) * 64]);
        #pragma unroll
        for (int i = 0; i < 2; ++i)
            gll16(Wt + (size_t)(col0 + w * 16 + i * 8 + srow) * DMODEL + k0 + sblk * 8,
                  &Ws[(w * 16 + i * 8) * 64]);
        asm volatile("s_waitcnt vmcnt(0)" ::: "memory");
        __syncthreads();

        #pragma unroll
        for (int ks = 0; ks < 2; ++ks) {
            short8 a[4], b[2];
            #pragma unroll
            for (int m = 0; m < 4; ++m) {
                const int r = wr * 64 + m * 16 + l15;
                a[m] = *(const short8*)&Xs[r * 64 + (((ks * 4 + l4) ^ (r & 7)) << 3)];
            }
            #pragma unroll
            for (int n = 0; n < 2; ++n) {
                const int r = wc * 32 + n * 16 + l15;
                b[n] = *(const short8*)&Ws[r * 64 + (((ks * 4 + l4) ^ (r & 7)) << 3)];
            }
            #pragma unroll
            for (int m = 0; m < 4; ++m)
                #pragma unroll
                for (int n = 0; n < 2; ++n)
                    acc[m][n] = __builtin_amdgcn_mfma_f32_16x16x32_bf16(
                        a[m], b[n], acc[m][n], 0, 0, 0);
        }
    }

    float bl[2];
    #pragma unroll
    for (int n = 0; n < 2; ++n)
        bl[n] = bias[col0 + wc * 32 + n * 16 + l15];

    #pragma unroll
    for (int m = 0; m < 4; ++m)
        #pragma unroll
        for (int n = 0; n < 2; ++n) {
            const int gc = col0 + wc * 32 + n * 16 + l15;
            #pragma unroll
            for (int reg = 0; reg < 4; ++reg) {
                const int gr = row0 + wr * 64 + m * 16 + l4 * 4 + reg;
                out[(size_t)gr * DMODEL + gc] = acc[m][n][reg] + bl[n];
            }
        }
}

// ---------------------------------------------------------------------------
// Attention (R9-proven, unchanged): 64 q-rows/block, grid 1024 = 4 blocks/CU,
// K dbuf + counted vmcnt, V reg prefetch, coalesced P store, 2 barriers/tile.
// ---------------------------------------------------------------------------
__device__ __forceinline__ int vt_off(int d, int jblk) {
    return d * 64 + ((jblk ^ ((d ^ (d >> 3)) & 7)) << 3);
}

__global__ __launch_bounds__(256)
void attn_mfma(const unsigned short* __restrict__ qg, const unsigned short* __restrict__ kg,
               const unsigned short* __restrict__ vg, float* __restrict__ attn,
               unsigned short* __restrict__ ctx)
{
    __shared__ unsigned short Ks[2 * 64 * 64];
    __shared__ unsigned short Vt[64 * 64];
    __shared__ unsigned short Ps[64 * 88];

    const int tid = threadIdx.x;
    const int lane = tid & 63, w = tid >> 6;
    const int l15 = lane & 15, l4 = lane >> 4;

    const int i0 = blockIdx.x;
    const int local = i0 >> 3;
    const int bh = (i0 & 7) * 4 + (local & 3);
    const int qx = local >> 2;
    const int qb = (bh & 1) ? (31 - qx) : qx;
    const int row0 = qb * 64;

    const int srow = lane >> 3;
    const int sblk = (lane & 7) ^ srow;

    const float C2 = 0.18033688011112042f;   // 0.125 * log2(e)

    const unsigned short* qh = qg + (size_t)bh * S_LEN * HD;
    const unsigned short* kh = kg + (size_t)bh * S_LEN * HD;
    const unsigned short* vh = vg + (size_t)bh * S_LEN * HD;
    float* attnh = attn + (size_t)bh * S_LEN * S_LEN;

    short8 qa[2];
    #pragma unroll
    for (int ks = 0; ks < 2; ++ks)
        qa[ks] = *(const short8*)(qh + (size_t)(row0 + w * 16 + l15) * HD + ks * 32 + l4 * 8);

    const int nt = qb + 1;
    const int jj0 = tid >> 3, d0v = (tid & 7) * 8;

    // ---- pass 1: row sums; K dbuf + counted vmcnt ----
    #pragma unroll
    for (int i = 0; i < 2; ++i)
        gll16(kh + (size_t)(w * 16 + i * 8 + srow) * HD + sblk * 8,
              &Ks[(w * 16 + i * 8) * 64]);

    float lsum[4] = {};
    for (int jt = 0; jt < nt; ++jt) {
        const int cur = jt & 1;
        __syncthreads();
        if (jt + 1 < nt) {
            #pragma unroll
            for (int i = 0; i < 2; ++i)
                gll16(kh + (size_t)((jt + 1) * 64 + w * 16 + i * 8 + srow) * HD + sblk * 8,
                      &Ks[(cur ^ 1) * 4096 + (w * 16 + i * 8) * 64]);
            asm volatile("s_waitcnt vmcnt(2)" ::: "memory");
        } else {
            asm volatile("s_waitcnt vmcnt(0)" ::: "memory");
        }
        __syncthreads();

        floatx4 sf[4] = {};
        #pragma unroll
        for (int ks = 0; ks < 2; ++ks) {
            short8 kb[4];
            #pragma unroll
            for (int c = 0; c < 4; ++c) {
                const int r = c * 16 + l15;
                kb[c] = *(const short8*)&Ks[cur * 4096 + r * 64
                                            + (((ks * 4 + l4) ^ (r & 7)) << 3)];
            }
            #pragma unroll
            for (int c = 0; c < 4; ++c)
                sf[c] = __builtin_amdgcn_mfma_f32_16x16x32_bf16(qa[ks], kb[c], sf[c], 0, 0, 0);
        }

        const int rbase = row0 + w * 16;
        if (jt * 64 + 63 <= rbase) {
            #pragma unroll
            for (int c = 0; c < 4; ++c)
                #pragma unroll
                for (int reg = 0; reg < 4; ++reg)
                    lsum[reg] += exp2f(sf[c][reg] * C2);
        } else {
            #pragma unroll
            for (int c = 0; c < 4; ++c) {
                const int jcol = jt * 64 + c * 16 + l15;
                #pragma unroll
                for (int reg = 0; reg < 4; ++reg) {
                    const int grow = rbase + l4 * 4 + reg;
                    lsum[reg] += (jcol <= grow) ? exp2f(sf[c][reg] * C2) : 0.f;
                }
            }
        }
    }

    float nl2[4];
    #pragma unroll
    for (int reg = 0; reg < 4; ++reg) {
        float s = lsum[reg];
        #pragma unroll
        for (int off = 1; off < 16; off <<= 1)
            s += __shfl_xor(s, off);
        nl2[reg] = -__log2f(s);
    }

    // ---- pass 2: P write + PV; 2 barriers/tile ----
    floatx4 o[4] = {};

    __syncthreads();
    #pragma unroll
    for (int i = 0; i < 2; ++i)
        gll16(kh + (size_t)(w * 16 + i * 8 + srow) * HD + sblk * 8,
              &Ks[(w * 16 + i * 8) * 64]);
    ushort8 vA0 = *(const ushort8*)(vh + (size_t)jj0 * HD + d0v);
    ushort8 vA1 = *(const ushort8*)(vh + (size_t)(jj0 + 32) * HD + d0v);
    ushort8 vB0, vB1;

    auto p2_iter = [&](int jt, int buf, ushort8& vc0, ushort8& vc1,
                       ushort8& vn0, ushort8& vn1) {
        if (jt + 1 < nt) {
            #pragma unroll
            for (int i = 0; i < 2; ++i)
                gll16(kh + (size_t)((jt + 1) * 64 + w * 16 + i * 8 + srow) * HD + sblk * 8,
                      &Ks[(buf ^ 1) * 4096 + (w * 16 + i * 8) * 64]);
            vn0 = *(const ushort8*)(vh + (size_t)((jt + 1) * 64 + jj0) * HD + d0v);
            vn1 = *(const ushort8*)(vh + (size_t)((jt + 1) * 64 + jj0 + 32) * HD + d0v);
            asm volatile("s_waitcnt vmcnt(4)" ::: "memory");
        } else {
            asm volatile("s_waitcnt vmcnt(0)" ::: "memory");
        }
        __syncthreads();

        #pragma unroll
        for (int e = 0; e < 8; ++e) {
            Vt[vt_off(d0v + e, jj0 >> 3) + (jj0 & 7)] = vc0[e];
            Vt[vt_off(d0v + e, (jj0 + 32) >> 3) + ((jj0 + 32) & 7)] = vc1[e];
        }

        floatx4 sf[4] = {};
        #pragma unroll
        for (int ks = 0; ks < 2; ++ks) {
            short8 kb[4];
            #pragma unroll
            for (int c = 0; c < 4; ++c) {
                const int r = c * 16 + l15;
                kb[c] = *(const short8*)&Ks[buf * 4096 + r * 64
                                            + (((ks * 4 + l4) ^ (r & 7)) << 3)];
            }
            #pragma unroll
            for (int c = 0; c < 4; ++c)
                sf[c] = __builtin_amdgcn_mfma_f32_16x16x32_bf16(qa[ks], kb[c], sf[c], 0, 0, 0);
        }

        const int rbase = row0 + w * 16;
        const bool full = (jt * 64 + 63 <= rbase);
        #pragma unroll
        for (int c = 0; c < 4; ++c) {
            const int jcol = jt * 64 + c * 16 + l15;
            #pragma unroll
            for (int reg = 0; reg < 4; ++reg) {
                const int rl = w * 16 + l4 * 4 + reg;
                float p = exp2f(fmaf(sf[c][reg], C2, nl2[reg]));
                if (!full && jcol > rbase + l4 * 4 + reg) p = 0.f;
                Ps[rl * 88 + c * 16 + l15] = f2b(p);
            }
        }
        __syncthreads();

        #pragma unroll
        for (int i2 = 0; i2 < 4; ++i2) {
            const int idx = tid + i2 * 256;
            const int r = idx >> 4, c4 = (idx & 15) * 4;
            const ushort4 pb = *(const ushort4*)&Ps[r * 88 + c4];
            float4 pf;
            pf.x = b2f(pb.x); pf.y = b2f(pb.y); pf.z = b2f(pb.z); pf.w = b2f(pb.w);
            *(float4*)(attnh + (size_t)(row0 + r) * S_LEN + jt * 64 + c4) = pf;
        }

        #pragma unroll
        for (int ks = 0; ks < 2; ++ks) {
            const short8 pa = *(const short8*)&Ps[(w * 16 + l15) * 88 + ks * 32 + l4 * 8];
            #pragma unroll
            for (int c = 0; c < 4; ++c) {
                const short8 vb = *(const short8*)&Vt[vt_off(c * 16 + l15, ks * 4 + l4)];
                o[c] = __builtin_amdgcn_mfma_f32_16x16x32_bf16(pa, vb, o[c], 0, 0, 0);
            }
        }
    };

    for (int jt2 = 0; jt2 < nt; jt2 += 2) {
        p2_iter(jt2, 0, vA0, vA1, vB0, vB1);
        if (jt2 + 1 < nt)
            p2_iter(jt2 + 1, 1, vB0, vB1, vA0, vA1);
    }

    // context out (bf16, [B, S, H*64])
    const int b = bh >> 4, h = bh & 15;
    #pragma unroll
    for (int c = 0; c < 4; ++c)
        #pragma unroll
        for (int reg = 0; reg < 4; ++reg) {
            const int gr = row0 + w * 16 + l4 * 4 + reg;
            const int d = c * 16 + l15;
            ctx[((size_t)b * S_LEN + gr) * DMODEL + h * HD + d] = f2b(o[c][reg]);
        }

    // zero-fill strictly-above-diagonal tiles
    const float4 z4 = {0.f, 0.f, 0.f, 0.f};
    for (int jt = nt; jt < S_LEN / 64; ++jt) {
        #pragma unroll
        for (int i = 0; i < 4; ++i) {
            const int idx = tid + i * 256;
            const int r = idx >> 4, off = (idx & 15) * 4;
            *(float4*)(attnh + (size_t)(row0 + r) * S_LEN + jt * 64 + off) = z4;
        }
    }
}

// ---------------------------------------------------------------------------
extern "C" void kernel_launch(void* const* d_in, const int* in_sizes, int n_in,
                              void* d_out, int out_size, void* d_ws, size_t ws_size,
                              hipStream_t stream)
{
    const float* Q  = (const float*)d_in[0];
    const float* K  = (const float*)d_in[1];
    const float* V  = (const float*)d_in[2];
    const float* Wq = (const float*)d_in[4];
    const float* bq = (const float*)d_in[5];
    const float* Wk = (const float*)d_in[6];
    const float* bk = (const float*)d_in[7];
    const float* Wv = (const float*)d_in[8];
    const float* bv = (const float*)d_in[9];
    const float* Wo = (const float*)d_in[10];
    const float* bo = (const float*)d_in[11];

    float* out  = (float*)d_out;
    float* attn = out + (size_t)NBATCH * S_LEN * DMODEL;

    const size_t per = (size_t)NBATCH * S_LEN * DMODEL;
    const size_t wsz = (size_t)DMODEL * DMODEL;
    unsigned short* Wtq = (unsigned short*)d_ws;
    unsigned short* Wtk = Wtq + wsz;
    unsigned short* Wtv = Wtk + wsz;
    unsigned short* Wto = Wtv + wsz;
    unsigned short* qhw = Wto + wsz;
    unsigned short* khw = qhw + per;
    unsigned short* vhw = khw + per;
    unsigned short* ctx = vhw + per;

    transpose_w<<<dim3(16, 16, 4), 256, 0, stream>>>(Wq, Wk, Wv, Wo, Wtq, Wtk, Wtv, Wto);

    gemm_qkv<<<dim3(DMODEL / 128, (NBATCH * S_LEN) / 128, 3), 256, 0, stream>>>(
        Q, K, V, Wtq, Wtk, Wtv, bq, bk, bv, qhw, khw, vhw);

    attn_mfma<<<1024, 256, 0, stream>>>(qhw, khw, vhw, attn, ctx);

    gemm_out<<<dim3(DMODEL / 64, (NBATCH * S_LEN) / 128), 256, 0, stream>>>(
        ctx, Wto, bo, out);
}

// Round 12
// 250.268 us; speedup vs baseline: 1.1122x; 1.1122x over previous
//
#include <hip/hip_runtime.h>
#include <math.h>

#define S_LEN 2048
#define DMODEL 1024
#define NHEAD 16
#define HD 64
#define NBATCH 2

using short8  = __attribute__((ext_vector_type(8))) short;
using ushort8 = __attribute__((ext_vector_type(8))) unsigned short;
using floatx4 = __attribute__((ext_vector_type(4))) float;

__device__ __forceinline__ unsigned short f2b(float f) {
    unsigned int u = __float_as_uint(f);
    unsigned int r = (u + 0x7FFFu + ((u >> 16) & 1u)) >> 16;
    return (unsigned short)r;
}
__device__ __forceinline__ float b2f(unsigned short b) {
    return __uint_as_float(((unsigned int)b) << 16);
}

// async global->LDS, 16B per lane; LDS dest = wave-uniform base + lane*16
__device__ __forceinline__ void gll16(const void* g, void* l) {
    __builtin_amdgcn_global_load_lds(
        (const __attribute__((address_space(1))) unsigned int*)g,
        (__attribute__((address_space(3))) unsigned int*)l, 16, 0, 0);
}

// ---------------------------------------------------------------------------
// fp32 -> bf16 convert; z selects Q/K/V
// ---------------------------------------------------------------------------
__global__ __launch_bounds__(256)
void convert_bf16(const float* __restrict__ S0, const float* __restrict__ S1,
                  const float* __restrict__ S2,
                  unsigned short* __restrict__ D0, unsigned short* __restrict__ D1,
                  unsigned short* __restrict__ D2, int n4)
{
    const float* src = (blockIdx.z == 0) ? S0 : (blockIdx.z == 1) ? S1 : S2;
    unsigned short* dst = (blockIdx.z == 0) ? D0 : (blockIdx.z == 1) ? D1 : D2;
    int i = blockIdx.x * 256 + threadIdx.x;
    if (i < n4) {
        float4 v = ((const float4*)src)[i];
        ushort4 o;
        o.x = f2b(v.x); o.y = f2b(v.y); o.z = f2b(v.z); o.w = f2b(v.w);
        ((ushort4*)dst)[i] = o;
    }
}

// ---------------------------------------------------------------------------
__global__ __launch_bounds__(256)
void transpose_w(const float* __restrict__ W0, const float* __restrict__ W1,
                 const float* __restrict__ W2, const float* __restrict__ W3,
                 unsigned short* __restrict__ T0, unsigned short* __restrict__ T1,
                 unsigned short* __restrict__ T2, unsigned short* __restrict__ T3)
{
    __shared__ float t[64][65];
    const float* W; unsigned short* T;
    switch (blockIdx.z) {
        case 0: W = W0; T = T0; break;
        case 1: W = W1; T = T1; break;
        case 2: W = W2; T = T2; break;
        default: W = W3; T = T3; break;
    }
    const int tid = threadIdx.x;
    const int c0 = blockIdx.x * 64;
    const int r0 = blockIdx.y * 64;
    #pragma unroll
    for (int i = 0; i < 4; ++i) {
        int c = tid + i * 256;
        int r = c >> 4, off = (c & 15) * 4;
        float4 v = *(const float4*)(W + (size_t)(r0 + r) * DMODEL + c0 + off);
        t[r][off + 0] = v.x; t[r][off + 1] = v.y;
        t[r][off + 2] = v.z; t[r][off + 3] = v.w;
    }
    __syncthreads();
    #pragma unroll
    for (int i = 0; i < 4; ++i) {
        int c = tid + i * 256;
        int n = c >> 4, off = (c & 15) * 4;
        ushort4 o;
        o.x = f2b(t[off + 0][n]); o.y = f2b(t[off + 1][n]);
        o.z = f2b(t[off + 2][n]); o.w = f2b(t[off + 3][n]);
        *(ushort4*)(T + (size_t)(c0 + n) * DMODEL + r0 + off) = o;
    }
}

// ---------------------------------------------------------------------------
// QKV GEMM, tile 128x128, BK=64, global_load_lds staging with XOR swizzle.
// ---------------------------------------------------------------------------
__global__ __launch_bounds__(256)
void gemm_qkv(const unsigned short* __restrict__ X0, const unsigned short* __restrict__ X1,
              const unsigned short* __restrict__ X2,
              const unsigned short* __restrict__ W0, const unsigned short* __restrict__ W1,
              const unsigned short* __restrict__ W2,
              const float* __restrict__ b0, const float* __restrict__ b1,
              const float* __restrict__ b2,
              unsigned short* __restrict__ o0, unsigned short* __restrict__ o1,
              unsigned short* __restrict__ o2)
{
    __shared__ unsigned short Xs[128 * 64];
    __shared__ unsigned short Ws[128 * 64];

    const unsigned short* X  = (blockIdx.z == 0) ? X0 : (blockIdx.z == 1) ? X1 : X2;
    const unsigned short* Wt = (blockIdx.z == 0) ? W0 : (blockIdx.z == 1) ? W1 : W2;
    const float* bias        = (blockIdx.z == 0) ? b0 : (blockIdx.z == 1) ? b1 : b2;
    unsigned short* outp     = (blockIdx.z == 0) ? o0 : (blockIdx.z == 1) ? o1 : o2;

    const int tid = threadIdx.x;
    const int lane = tid & 63, w = tid >> 6;
    const int l15 = lane & 15, l4 = lane >> 4;
    const int wr = w >> 1, wc = w & 1;
    const int row0 = blockIdx.y * 128;
    const int col0 = blockIdx.x * 128;

    const int srow = lane >> 3;
    const int sblk = (lane & 7) ^ srow;

    floatx4 acc[4][4] = {};

    for (int k0 = 0; k0 < DMODEL; k0 += 64) {
        __syncthreads();
        #pragma unroll
        for (int i = 0; i < 4; ++i)
            gll16(X + (size_t)(row0 + w * 32 + i * 8 + srow) * DMODEL + k0 + sblk * 8,
                  &Xs[(w * 32 + i * 8) * 64]);
        #pragma unroll
        for (int i = 0; i < 4; ++i)
            gll16(Wt + (size_t)(col0 + w * 32 + i * 8 + srow) * DMODEL + k0 + sblk * 8,
                  &Ws[(w * 32 + i * 8) * 64]);
        asm volatile("s_waitcnt vmcnt(0)" ::: "memory");
        __syncthreads();

        #pragma unroll
        for (int ks = 0; ks < 2; ++ks) {
            short8 a[4], b[4];
            #pragma unroll
            for (int m = 0; m < 4; ++m) {
                const int r = wr * 64 + m * 16 + l15;
                a[m] = *(const short8*)&Xs[r * 64 + (((ks * 4 + l4) ^ (r & 7)) << 3)];
            }
            #pragma unroll
            for (int n = 0; n < 4; ++n) {
                const int r = wc * 64 + n * 16 + l15;
                b[n] = *(const short8*)&Ws[r * 64 + (((ks * 4 + l4) ^ (r & 7)) << 3)];
            }
            #pragma unroll
            for (int m = 0; m < 4; ++m)
                #pragma unroll
                for (int n = 0; n < 4; ++n)
                    acc[m][n] = __builtin_amdgcn_mfma_f32_16x16x32_bf16(
                        a[m], b[n], acc[m][n], 0, 0, 0);
        }
    }

    float bl[4];
    #pragma unroll
    for (int n = 0; n < 4; ++n)
        bl[n] = bias[col0 + wc * 64 + n * 16 + l15];

    #pragma unroll
    for (int m = 0; m < 4; ++m)
        #pragma unroll
        for (int n = 0; n < 4; ++n) {
            const int gc = col0 + wc * 64 + n * 16 + l15;
            const int h = gc >> 6, d = gc & 63;
            #pragma unroll
            for (int reg = 0; reg < 4; ++reg) {
                const int gr = row0 + wr * 64 + m * 16 + l4 * 4 + reg;
                const int bb = gr >> 11, s = gr & 2047;
                outp[(((size_t)bb * NHEAD + h) * S_LEN + s) * HD + d] =
                    f2b(acc[m][n][reg] + bl[n]);
            }
        }
}

// ---------------------------------------------------------------------------
// Output projection GEMM, tile 128x64 -> grid (16,32)=512 wg = 2 blocks/CU.
// ---------------------------------------------------------------------------
__global__ __launch_bounds__(256)
void gemm_out(const unsigned short* __restrict__ X, const unsigned short* __restrict__ Wt,
              const float* __restrict__ bias, float* __restrict__ out)
{
    __shared__ unsigned short Xs[128 * 64];
    __shared__ unsigned short Ws[64 * 64];

    const int tid = threadIdx.x;
    const int lane = tid & 63, w = tid >> 6;
    const int l15 = lane & 15, l4 = lane >> 4;
    const int wr = w >> 1, wc = w & 1;
    const int row0 = blockIdx.y * 128;
    const int col0 = blockIdx.x * 64;

    const int srow = lane >> 3;
    const int sblk = (lane & 7) ^ srow;

    floatx4 acc[4][2] = {};

    for (int k0 = 0; k0 < DMODEL; k0 += 64) {
        __syncthreads();
        #pragma unroll
        for (int i = 0; i < 4; ++i)
            gll16(X + (size_t)(row0 + w * 32 + i * 8 + srow) * DMODEL + k0 + sblk * 8,
                  &Xs[(w * 32 + i * 8) * 64]);
        #pragma unroll
        for (int i = 0; i < 2; ++i)
            gll16(Wt + (size_t)(col0 + w * 16 + i * 8 + srow) * DMODEL + k0 + sblk * 8,
                  &Ws[(w * 16 + i * 8) * 64]);
        asm volatile("s_waitcnt vmcnt(0)" ::: "memory");
        __syncthreads();

        #pragma unroll
        for (int ks = 0; ks < 2; ++ks) {
            short8 a[4], b[2];
            #pragma unroll
            for (int m = 0; m < 4; ++m) {
                const int r = wr * 64 + m * 16 + l15;
                a[m] = *(const short8*)&Xs[r * 64 + (((ks * 4 + l4) ^ (r & 7)) << 3)];
            }
            #pragma unroll
            for (int n = 0; n < 2; ++n) {
                const int r = wc * 32 + n * 16 + l15;
                b[n] = *(const short8*)&Ws[r * 64 + (((ks * 4 + l4) ^ (r & 7)) << 3)];
            }
            #pragma unroll
            for (int m = 0; m < 4; ++m)
                #pragma unroll
                for (int n = 0; n < 2; ++n)
                    acc[m][n] = __builtin_amdgcn_mfma_f32_16x16x32_bf16(
                        a[m], b[n], acc[m][n], 0, 0, 0);
        }
    }

    float bl[2];
    #pragma unroll
    for (int n = 0; n < 2; ++n)
        bl[n] = bias[col0 + wc * 32 + n * 16 + l15];

    #pragma unroll
    for (int m = 0; m < 4; ++m)
        #pragma unroll
        for (int n = 0; n < 2; ++n) {
            const int gc = col0 + wc * 32 + n * 16 + l15;
            #pragma unroll
            for (int reg = 0; reg < 4; ++reg) {
                const int gr = row0 + wr * 64 + m * 16 + l4 * 4 + reg;
                out[(size_t)gr * DMODEL + gc] = acc[m][n][reg] + bl[n];
            }
        }
}

// ---------------------------------------------------------------------------
// Attention (R9 structure). ONLY change vs R9: attn P-stores and zero-fill
// use __builtin_nontemporal_store (floatx4) — isolated L2-pollution probe.
// ---------------------------------------------------------------------------
__device__ __forceinline__ int vt_off(int d, int jblk) {
    return d * 64 + ((jblk ^ ((d ^ (d >> 3)) & 7)) << 3);
}

__global__ __launch_bounds__(256)
void attn_mfma(const unsigned short* __restrict__ qg, const unsigned short* __restrict__ kg,
               const unsigned short* __restrict__ vg, float* __restrict__ attn,
               unsigned short* __restrict__ ctx)
{
    __shared__ unsigned short Ks[2 * 64 * 64];
    __shared__ unsigned short Vt[64 * 64];
    __shared__ unsigned short Ps[64 * 88];

    const int tid = threadIdx.x;
    const int lane = tid & 63, w = tid >> 6;
    const int l15 = lane & 15, l4 = lane >> 4;

    const int i0 = blockIdx.x;
    const int local = i0 >> 3;
    const int bh = (i0 & 7) * 4 + (local & 3);
    const int qx = local >> 2;
    const int qb = (bh & 1) ? (31 - qx) : qx;
    const int row0 = qb * 64;

    const int srow = lane >> 3;
    const int sblk = (lane & 7) ^ srow;

    const float C2 = 0.18033688011112042f;   // 0.125 * log2(e)

    const unsigned short* qh = qg + (size_t)bh * S_LEN * HD;
    const unsigned short* kh = kg + (size_t)bh * S_LEN * HD;
    const unsigned short* vh = vg + (size_t)bh * S_LEN * HD;
    float* attnh = attn + (size_t)bh * S_LEN * S_LEN;

    short8 qa[2];
    #pragma unroll
    for (int ks = 0; ks < 2; ++ks)
        qa[ks] = *(const short8*)(qh + (size_t)(row0 + w * 16 + l15) * HD + ks * 32 + l4 * 8);

    const int nt = qb + 1;
    const int jj0 = tid >> 3, d0v = (tid & 7) * 8;

    // ---- pass 1: row sums; K dbuf + counted vmcnt ----
    #pragma unroll
    for (int i = 0; i < 2; ++i)
        gll16(kh + (size_t)(w * 16 + i * 8 + srow) * HD + sblk * 8,
              &Ks[(w * 16 + i * 8) * 64]);

    float lsum[4] = {};
    for (int jt = 0; jt < nt; ++jt) {
        const int cur = jt & 1;
        __syncthreads();
        if (jt + 1 < nt) {
            #pragma unroll
            for (int i = 0; i < 2; ++i)
                gll16(kh + (size_t)((jt + 1) * 64 + w * 16 + i * 8 + srow) * HD + sblk * 8,
                      &Ks[(cur ^ 1) * 4096 + (w * 16 + i * 8) * 64]);
            asm volatile("s_waitcnt vmcnt(2)" ::: "memory");
        } else {
            asm volatile("s_waitcnt vmcnt(0)" ::: "memory");
        }
        __syncthreads();

        floatx4 sf[4] = {};
        #pragma unroll
        for (int ks = 0; ks < 2; ++ks) {
            short8 kb[4];
            #pragma unroll
            for (int c = 0; c < 4; ++c) {
                const int r = c * 16 + l15;
                kb[c] = *(const short8*)&Ks[cur * 4096 + r * 64
                                            + (((ks * 4 + l4) ^ (r & 7)) << 3)];
            }
            #pragma unroll
            for (int c = 0; c < 4; ++c)
                sf[c] = __builtin_amdgcn_mfma_f32_16x16x32_bf16(qa[ks], kb[c], sf[c], 0, 0, 0);
        }

        const int rbase = row0 + w * 16;
        if (jt * 64 + 63 <= rbase) {
            #pragma unroll
            for (int c = 0; c < 4; ++c)
                #pragma unroll
                for (int reg = 0; reg < 4; ++reg)
                    lsum[reg] += exp2f(sf[c][reg] * C2);
        } else {
            #pragma unroll
            for (int c = 0; c < 4; ++c) {
                const int jcol = jt * 64 + c * 16 + l15;
                #pragma unroll
                for (int reg = 0; reg < 4; ++reg) {
                    const int grow = rbase + l4 * 4 + reg;
                    lsum[reg] += (jcol <= grow) ? exp2f(sf[c][reg] * C2) : 0.f;
                }
            }
        }
    }

    float nl2[4];
    #pragma unroll
    for (int reg = 0; reg < 4; ++reg) {
        float s = lsum[reg];
        #pragma unroll
        for (int off = 1; off < 16; off <<= 1)
            s += __shfl_xor(s, off);
        nl2[reg] = -__log2f(s);
    }

    // ---- pass 2: P write + PV; 2 barriers/tile ----
    floatx4 o[4] = {};

    __syncthreads();
    #pragma unroll
    for (int i = 0; i < 2; ++i)
        gll16(kh + (size_t)(w * 16 + i * 8 + srow) * HD + sblk * 8,
              &Ks[(w * 16 + i * 8) * 64]);
    ushort8 vA0 = *(const ushort8*)(vh + (size_t)jj0 * HD + d0v);
    ushort8 vA1 = *(const ushort8*)(vh + (size_t)(jj0 + 32) * HD + d0v);
    ushort8 vB0, vB1;

    auto p2_iter = [&](int jt, int buf, ushort8& vc0, ushort8& vc1,
                       ushort8& vn0, ushort8& vn1) {
        if (jt + 1 < nt) {
            #pragma unroll
            for (int i = 0; i < 2; ++i)
                gll16(kh + (size_t)((jt + 1) * 64 + w * 16 + i * 8 + srow) * HD + sblk * 8,
                      &Ks[(buf ^ 1) * 4096 + (w * 16 + i * 8) * 64]);
            vn0 = *(const ushort8*)(vh + (size_t)((jt + 1) * 64 + jj0) * HD + d0v);
            vn1 = *(const ushort8*)(vh + (size_t)((jt + 1) * 64 + jj0 + 32) * HD + d0v);
            asm volatile("s_waitcnt vmcnt(4)" ::: "memory");
        } else {
            asm volatile("s_waitcnt vmcnt(0)" ::: "memory");
        }
        __syncthreads();

        #pragma unroll
        for (int e = 0; e < 8; ++e) {
            Vt[vt_off(d0v + e, jj0 >> 3) + (jj0 & 7)] = vc0[e];
            Vt[vt_off(d0v + e, (jj0 + 32) >> 3) + ((jj0 + 32) & 7)] = vc1[e];
        }

        floatx4 sf[4] = {};
        #pragma unroll
        for (int ks = 0; ks < 2; ++ks) {
            short8 kb[4];
            #pragma unroll
            for (int c = 0; c < 4; ++c) {
                const int r = c * 16 + l15;
                kb[c] = *(const short8*)&Ks[buf * 4096 + r * 64
                                            + (((ks * 4 + l4) ^ (r & 7)) << 3)];
            }
            #pragma unroll
            for (int c = 0; c < 4; ++c)
                sf[c] = __builtin_amdgcn_mfma_f32_16x16x32_bf16(qa[ks], kb[c], sf[c], 0, 0, 0);
        }

        const int rbase = row0 + w * 16;
        const bool full = (jt * 64 + 63 <= rbase);
        #pragma unroll
        for (int c = 0; c < 4; ++c) {
            const int jcol = jt * 64 + c * 16 + l15;
            #pragma unroll
            for (int reg = 0; reg < 4; ++reg) {
                const int rl = w * 16 + l4 * 4 + reg;
                float p = exp2f(fmaf(sf[c][reg], C2, nl2[reg]));
                if (!full && jcol > rbase + l4 * 4 + reg) p = 0.f;
                Ps[rl * 88 + c * 16 + l15] = f2b(p);
            }
        }
        __syncthreads();

        // coalesced NONTEMPORAL attn tile write from Ps
        #pragma unroll
        for (int i2 = 0; i2 < 4; ++i2) {
            const int idx = tid + i2 * 256;
            const int r = idx >> 4, c4 = (idx & 15) * 4;
            const ushort4 pb = *(const ushort4*)&Ps[r * 88 + c4];
            floatx4 pf;
            pf[0] = b2f(pb.x); pf[1] = b2f(pb.y); pf[2] = b2f(pb.z); pf[3] = b2f(pb.w);
            __builtin_nontemporal_store(
                pf, (floatx4*)(attnh + (size_t)(row0 + r) * S_LEN + jt * 64 + c4));
        }

        #pragma unroll
        for (int ks = 0; ks < 2; ++ks) {
            const short8 pa = *(const short8*)&Ps[(w * 16 + l15) * 88 + ks * 32 + l4 * 8];
            #pragma unroll
            for (int c = 0; c < 4; ++c) {
                const short8 vb = *(const short8*)&Vt[vt_off(c * 16 + l15, ks * 4 + l4)];
                o[c] = __builtin_amdgcn_mfma_f32_16x16x32_bf16(pa, vb, o[c], 0, 0, 0);
            }
        }
    };

    for (int jt2 = 0; jt2 < nt; jt2 += 2) {
        p2_iter(jt2, 0, vA0, vA1, vB0, vB1);
        if (jt2 + 1 < nt)
            p2_iter(jt2 + 1, 1, vB0, vB1, vA0, vA1);
    }

    // context out (bf16, [B, S, H*64])
    const int b = bh >> 4, h = bh & 15;
    #pragma unroll
    for (int c = 0; c < 4; ++c)
        #pragma unroll
        for (int reg = 0; reg < 4; ++reg) {
            const int gr = row0 + w * 16 + l4 * 4 + reg;
            const int d = c * 16 + l15;
            ctx[((size_t)b * S_LEN + gr) * DMODEL + h * HD + d] = f2b(o[c][reg]);
        }

    // zero-fill strictly-above-diagonal tiles (nontemporal)
    const floatx4 z4 = {0.f, 0.f, 0.f, 0.f};
    for (int jt = nt; jt < S_LEN / 64; ++jt) {
        #pragma unroll
        for (int i = 0; i < 4; ++i) {
            const int idx = tid + i * 256;
            const int r = idx >> 4, off = (idx & 15) * 4;
            __builtin_nontemporal_store(
                z4, (floatx4*)(attnh + (size_t)(row0 + r) * S_LEN + jt * 64 + off));
        }
    }
}

// ---------------------------------------------------------------------------
extern "C" void kernel_launch(void* const* d_in, const int* in_sizes, int n_in,
                              void* d_out, int out_size, void* d_ws, size_t ws_size,
                              hipStream_t stream)
{
    const float* Q  = (const float*)d_in[0];
    const float* K  = (const float*)d_in[1];
    const float* V  = (const float*)d_in[2];
    const float* Wq = (const float*)d_in[4];
    const float* bq = (const float*)d_in[5];
    const float* Wk = (const float*)d_in[6];
    const float* bk = (const float*)d_in[7];
    const float* Wv = (const float*)d_in[8];
    const float* bv = (const float*)d_in[9];
    const float* Wo = (const float*)d_in[10];
    const float* bo = (const float*)d_in[11];

    float* out  = (float*)d_out;
    float* attn = out + (size_t)NBATCH * S_LEN * DMODEL;

    const size_t per = (size_t)NBATCH * S_LEN * DMODEL;
    const size_t wsz = (size_t)DMODEL * DMODEL;
    unsigned short* Xq  = (unsigned short*)d_ws;
    unsigned short* Xk  = Xq + per;
    unsigned short* Xv  = Xk + per;
    unsigned short* Wtq = Xv + per;
    unsigned short* Wtk = Wtq + wsz;
    unsigned short* Wtv = Wtk + wsz;
    unsigned short* Wto = Wtv + wsz;
    unsigned short* qhw = Wto + wsz;
    unsigned short* khw = qhw + per;
    unsigned short* vhw = khw + per;
    unsigned short* ctx = vhw + per;

    const int n4 = (int)(per / 4);
    convert_bf16<<<dim3((n4 + 255) / 256, 1, 3), 256, 0, stream>>>(
        Q, K, V, Xq, Xk, Xv, n4);
    transpose_w<<<dim3(16, 16, 4), 256, 0, stream>>>(Wq, Wk, Wv, Wo, Wtq, Wtk, Wtv, Wto);

    gemm_qkv<<<dim3(DMODEL / 128, (NBATCH * S_LEN) / 128, 3), 256, 0, stream>>>(
        Xq, Xk, Xv, Wtq, Wtk, Wtv, bq, bk, bv, qhw, khw, vhw);

    attn_mfma<<<1024, 256, 0, stream>>>(qhw, khw, vhw, attn, ctx);

    gemm_out<<<dim3(DMODEL / 64, (NBATCH * S_LEN) / 128), 256, 0, stream>>>(
        ctx, Wto, bo, out);
}

// Round 13
// 231.326 us; speedup vs baseline: 1.2032x; 1.0819x over previous
//
#include <hip/hip_runtime.h>
#include <math.h>

#define S_LEN 2048
#define DMODEL 1024
#define NHEAD 16
#define HD 64
#define NBATCH 2

using short8  = __attribute__((ext_vector_type(8))) short;
using ushort8 = __attribute__((ext_vector_type(8))) unsigned short;
using floatx4 = __attribute__((ext_vector_type(4))) float;

__device__ __forceinline__ unsigned short f2b(float f) {
    unsigned int u = __float_as_uint(f);
    unsigned int r = (u + 0x7FFFu + ((u >> 16) & 1u)) >> 16;
    return (unsigned short)r;
}
__device__ __forceinline__ float b2f(unsigned short b) {
    return __uint_as_float(((unsigned int)b) << 16);
}

// async global->LDS, 16B per lane; LDS dest = wave-uniform base + lane*16
__device__ __forceinline__ void gll16(const void* g, void* l) {
    __builtin_amdgcn_global_load_lds(
        (const __attribute__((address_space(1))) unsigned int*)g,
        (__attribute__((address_space(3))) unsigned int*)l, 16, 0, 0);
}

// ---------------------------------------------------------------------------
// fp32 -> bf16 convert; z selects Q/K/V
// ---------------------------------------------------------------------------
__global__ __launch_bounds__(256)
void convert_bf16(const float* __restrict__ S0, const float* __restrict__ S1,
                  const float* __restrict__ S2,
                  unsigned short* __restrict__ D0, unsigned short* __restrict__ D1,
                  unsigned short* __restrict__ D2, int n4)
{
    const float* src = (blockIdx.z == 0) ? S0 : (blockIdx.z == 1) ? S1 : S2;
    unsigned short* dst = (blockIdx.z == 0) ? D0 : (blockIdx.z == 1) ? D1 : D2;
    int i = blockIdx.x * 256 + threadIdx.x;
    if (i < n4) {
        float4 v = ((const float4*)src)[i];
        ushort4 o;
        o.x = f2b(v.x); o.y = f2b(v.y); o.z = f2b(v.z); o.w = f2b(v.w);
        ((ushort4*)dst)[i] = o;
    }
}

// ---------------------------------------------------------------------------
__global__ __launch_bounds__(256)
void transpose_w(const float* __restrict__ W0, const float* __restrict__ W1,
                 const float* __restrict__ W2, const float* __restrict__ W3,
                 unsigned short* __restrict__ T0, unsigned short* __restrict__ T1,
                 unsigned short* __restrict__ T2, unsigned short* __restrict__ T3)
{
    __shared__ float t[64][65];
    const float* W; unsigned short* T;
    switch (blockIdx.z) {
        case 0: W = W0; T = T0; break;
        case 1: W = W1; T = T1; break;
        case 2: W = W2; T = T2; break;
        default: W = W3; T = T3; break;
    }
    const int tid = threadIdx.x;
    const int c0 = blockIdx.x * 64;
    const int r0 = blockIdx.y * 64;
    #pragma unroll
    for (int i = 0; i < 4; ++i) {
        int c = tid + i * 256;
        int r = c >> 4, off = (c & 15) * 4;
        float4 v = *(const float4*)(W + (size_t)(r0 + r) * DMODEL + c0 + off);
        t[r][off + 0] = v.x; t[r][off + 1] = v.y;
        t[r][off + 2] = v.z; t[r][off + 3] = v.w;
    }
    __syncthreads();
    #pragma unroll
    for (int i = 0; i < 4; ++i) {
        int c = tid + i * 256;
        int n = c >> 4, off = (c & 15) * 4;
        ushort4 o;
        o.x = f2b(t[off + 0][n]); o.y = f2b(t[off + 1][n]);
        o.z = f2b(t[off + 2][n]); o.w = f2b(t[off + 3][n]);
        *(ushort4*)(T + (size_t)(c0 + n) * DMODEL + r0 + off) = o;
    }
}

// ---------------------------------------------------------------------------
// QKV GEMM, tile 128x128, BK=64, global_load_lds staging with XOR swizzle.
// z==0/1 (Q/K): head-major [B,H,S,64]. z==2 (V): TRANSPOSED [B,H,64,S]
// (d-major) so attention can stage V via global_load_lds like K.
// ---------------------------------------------------------------------------
__global__ __launch_bounds__(256)
void gemm_qkv(const unsigned short* __restrict__ X0, const unsigned short* __restrict__ X1,
              const unsigned short* __restrict__ X2,
              const unsigned short* __restrict__ W0, const unsigned short* __restrict__ W1,
              const unsigned short* __restrict__ W2,
              const float* __restrict__ b0, const float* __restrict__ b1,
              const float* __restrict__ b2,
              unsigned short* __restrict__ o0, unsigned short* __restrict__ o1,
              unsigned short* __restrict__ o2)
{
    __shared__ unsigned short Xs[128 * 64];
    __shared__ unsigned short Ws[128 * 64];

    const unsigned short* X  = (blockIdx.z == 0) ? X0 : (blockIdx.z == 1) ? X1 : X2;
    const unsigned short* Wt = (blockIdx.z == 0) ? W0 : (blockIdx.z == 1) ? W1 : W2;
    const float* bias        = (blockIdx.z == 0) ? b0 : (blockIdx.z == 1) ? b1 : b2;
    unsigned short* outp     = (blockIdx.z == 0) ? o0 : (blockIdx.z == 1) ? o1 : o2;

    const int tid = threadIdx.x;
    const int lane = tid & 63, w = tid >> 6;
    const int l15 = lane & 15, l4 = lane >> 4;
    const int wr = w >> 1, wc = w & 1;
    const int row0 = blockIdx.y * 128;
    const int col0 = blockIdx.x * 128;

    const int srow = lane >> 3;
    const int sblk = (lane & 7) ^ srow;

    floatx4 acc[4][4] = {};

    for (int k0 = 0; k0 < DMODEL; k0 += 64) {
        __syncthreads();
        #pragma unroll
        for (int i = 0; i < 4; ++i)
            gll16(X + (size_t)(row0 + w * 32 + i * 8 + srow) * DMODEL + k0 + sblk * 8,
                  &Xs[(w * 32 + i * 8) * 64]);
        #pragma unroll
        for (int i = 0; i < 4; ++i)
            gll16(Wt + (size_t)(col0 + w * 32 + i * 8 + srow) * DMODEL + k0 + sblk * 8,
                  &Ws[(w * 32 + i * 8) * 64]);
        asm volatile("s_waitcnt vmcnt(0)" ::: "memory");
        __syncthreads();

        #pragma unroll
        for (int ks = 0; ks < 2; ++ks) {
            short8 a[4], b[4];
            #pragma unroll
            for (int m = 0; m < 4; ++m) {
                const int r = wr * 64 + m * 16 + l15;
                a[m] = *(const short8*)&Xs[r * 64 + (((ks * 4 + l4) ^ (r & 7)) << 3)];
            }
            #pragma unroll
            for (int n = 0; n < 4; ++n) {
                const int r = wc * 64 + n * 16 + l15;
                b[n] = *(const short8*)&Ws[r * 64 + (((ks * 4 + l4) ^ (r & 7)) << 3)];
            }
            #pragma unroll
            for (int m = 0; m < 4; ++m)
                #pragma unroll
                for (int n = 0; n < 4; ++n)
                    acc[m][n] = __builtin_amdgcn_mfma_f32_16x16x32_bf16(
                        a[m], b[n], acc[m][n], 0, 0, 0);
        }
    }

    float bl[4];
    #pragma unroll
    for (int n = 0; n < 4; ++n)
        bl[n] = bias[col0 + wc * 64 + n * 16 + l15];

    if (blockIdx.z != 2) {
        #pragma unroll
        for (int m = 0; m < 4; ++m)
            #pragma unroll
            for (int n = 0; n < 4; ++n) {
                const int gc = col0 + wc * 64 + n * 16 + l15;
                const int h = gc >> 6, d = gc & 63;
                #pragma unroll
                for (int reg = 0; reg < 4; ++reg) {
                    const int gr = row0 + wr * 64 + m * 16 + l4 * 4 + reg;
                    const int bb = gr >> 11, s = gr & 2047;
                    outp[(((size_t)bb * NHEAD + h) * S_LEN + s) * HD + d] =
                        f2b(acc[m][n][reg] + bl[n]);
                }
            }
    } else {
        // V transposed: [bh][d][s], 4 consecutive s per ushort4
        #pragma unroll
        for (int m = 0; m < 4; ++m)
            #pragma unroll
            for (int n = 0; n < 4; ++n) {
                const int gc = col0 + wc * 64 + n * 16 + l15;
                const int h = gc >> 6, d = gc & 63;
                const int s0 = row0 + wr * 64 + m * 16 + l4 * 4;
                const int bb = s0 >> 11, sr = s0 & 2047;
                ushort4 pk;
                pk.x = f2b(acc[m][n][0] + bl[n]);
                pk.y = f2b(acc[m][n][1] + bl[n]);
                pk.z = f2b(acc[m][n][2] + bl[n]);
                pk.w = f2b(acc[m][n][3] + bl[n]);
                *(ushort4*)(outp + (((size_t)bb * NHEAD + h) * HD + d) * S_LEN + sr) = pk;
            }
    }
}

// ---------------------------------------------------------------------------
// Output projection GEMM, tile 128x64 -> grid (16,32)=512 wg = 2 blocks/CU.
// ---------------------------------------------------------------------------
__global__ __launch_bounds__(256)
void gemm_out(const unsigned short* __restrict__ X, const unsigned short* __restrict__ Wt,
              const float* __restrict__ bias, float* __restrict__ out)
{
    __shared__ unsigned short Xs[128 * 64];
    __shared__ unsigned short Ws[64 * 64];

    const int tid = threadIdx.x;
    const int lane = tid & 63, w = tid >> 6;
    const int l15 = lane & 15, l4 = lane >> 4;
    const int wr = w >> 1, wc = w & 1;
    const int row0 = blockIdx.y * 128;
    const int col0 = blockIdx.x * 64;

    const int srow = lane >> 3;
    const int sblk = (lane & 7) ^ srow;

    floatx4 acc[4][2] = {};

    for (int k0 = 0; k0 < DMODEL; k0 += 64) {
        __syncthreads();
        #pragma unroll
        for (int i = 0; i < 4; ++i)
            gll16(X + (size_t)(row0 + w * 32 + i * 8 + srow) * DMODEL + k0 + sblk * 8,
                  &Xs[(w * 32 + i * 8) * 64]);
        #pragma unroll
        for (int i = 0; i < 2; ++i)
            gll16(Wt + (size_t)(col0 + w * 16 + i * 8 + srow) * DMODEL + k0 + sblk * 8,
                  &Ws[(w * 16 + i * 8) * 64]);
        asm volatile("s_waitcnt vmcnt(0)" ::: "memory");
        __syncthreads();

        #pragma unroll
        for (int ks = 0; ks < 2; ++ks) {
            short8 a[4], b[2];
            #pragma unroll
            for (int m = 0; m < 4; ++m) {
                const int r = wr * 64 + m * 16 + l15;
                a[m] = *(const short8*)&Xs[r * 64 + (((ks * 4 + l4) ^ (r & 7)) << 3)];
            }
            #pragma unroll
            for (int n = 0; n < 2; ++n) {
                const int r = wc * 32 + n * 16 + l15;
                b[n] = *(const short8*)&Ws[r * 64 + (((ks * 4 + l4) ^ (r & 7)) << 3)];
            }
            #pragma unroll
            for (int m = 0; m < 4; ++m)
                #pragma unroll
                for (int n = 0; n < 2; ++n)
                    acc[m][n] = __builtin_amdgcn_mfma_f32_16x16x32_bf16(
                        a[m], b[n], acc[m][n], 0, 0, 0);
        }
    }

    float bl[2];
    #pragma unroll
    for (int n = 0; n < 2; ++n)
        bl[n] = bias[col0 + wc * 32 + n * 16 + l15];

    #pragma unroll
    for (int m = 0; m < 4; ++m)
        #pragma unroll
        for (int n = 0; n < 2; ++n) {
            const int gc = col0 + wc * 32 + n * 16 + l15;
            #pragma unroll
            for (int reg = 0; reg < 4; ++reg) {
                const int gr = row0 + wr * 64 + m * 16 + l4 * 4 + reg;
                out[(size_t)gr * DMODEL + gc] = acc[m][n][reg] + bl[n];
            }
        }
}

// ---------------------------------------------------------------------------
// Attention: 64 q-rows/block, grid 1024 = 4 blocks/CU.
// Pass 1: K dbuf + counted vmcnt (R12). Pass 2: BOTH K and V staged via
// gll16 (V from its transposed global layout, same XOR swizzle as K).
// Ordering: vmcnt(0) pre-B retires K(jt); stage V(jt) then K(jt+1) after B
// (FIFO: V older); vmcnt(2) pre-C retires V(jt) while K(jt+1) flies.
// Single Vt buffer (safe: PV(jt-1) precedes B(jt) in program order).
// NT stores on attn writes (R12-proven).
// ---------------------------------------------------------------------------
__global__ __launch_bounds__(256)
void attn_mfma(const unsigned short* __restrict__ qg, const unsigned short* __restrict__ kg,
               const unsigned short* __restrict__ vtg, float* __restrict__ attn,
               unsigned short* __restrict__ ctx)
{
    __shared__ unsigned short Ks[2 * 64 * 64];
    __shared__ unsigned short Vt[64 * 64];
    __shared__ unsigned short Ps[64 * 88];

    const int tid = threadIdx.x;
    const int lane = tid & 63, w = tid >> 6;
    const int l15 = lane & 15, l4 = lane >> 4;

    const int i0 = blockIdx.x;
    const int local = i0 >> 3;
    const int bh = (i0 & 7) * 4 + (local & 3);
    const int qx = local >> 2;
    const int qb = (bh & 1) ? (31 - qx) : qx;
    const int row0 = qb * 64;

    const int srow = lane >> 3;
    const int sblk = (lane & 7) ^ srow;

    const float C2 = 0.18033688011112042f;   // 0.125 * log2(e)

    const unsigned short* qh = qg + (size_t)bh * S_LEN * HD;
    const unsigned short* kh = kg + (size_t)bh * S_LEN * HD;
    const unsigned short* vth = vtg + (size_t)bh * HD * S_LEN;   // [d][s]
    float* attnh = attn + (size_t)bh * S_LEN * S_LEN;

    short8 qa[2];
    #pragma unroll
    for (int ks = 0; ks < 2; ++ks)
        qa[ks] = *(const short8*)(qh + (size_t)(row0 + w * 16 + l15) * HD + ks * 32 + l4 * 8);

    const int nt = qb + 1;

    // ---- pass 1: row sums; K dbuf + counted vmcnt ----
    #pragma unroll
    for (int i = 0; i < 2; ++i)
        gll16(kh + (size_t)(w * 16 + i * 8 + srow) * HD + sblk * 8,
              &Ks[(w * 16 + i * 8) * 64]);

    float lsum[4] = {};
    for (int jt = 0; jt < nt; ++jt) {
        const int cur = jt & 1;
        __syncthreads();
        if (jt + 1 < nt) {
            #pragma unroll
            for (int i = 0; i < 2; ++i)
                gll16(kh + (size_t)((jt + 1) * 64 + w * 16 + i * 8 + srow) * HD + sblk * 8,
                      &Ks[(cur ^ 1) * 4096 + (w * 16 + i * 8) * 64]);
            asm volatile("s_waitcnt vmcnt(2)" ::: "memory");
        } else {
            asm volatile("s_waitcnt vmcnt(0)" ::: "memory");
        }
        __syncthreads();

        floatx4 sf[4] = {};
        #pragma unroll
        for (int ks = 0; ks < 2; ++ks) {
            short8 kb[4];
            #pragma unroll
            for (int c = 0; c < 4; ++c) {
                const int r = c * 16 + l15;
                kb[c] = *(const short8*)&Ks[cur * 4096 + r * 64
                                            + (((ks * 4 + l4) ^ (r & 7)) << 3)];
            }
            #pragma unroll
            for (int c = 0; c < 4; ++c)
                sf[c] = __builtin_amdgcn_mfma_f32_16x16x32_bf16(qa[ks], kb[c], sf[c], 0, 0, 0);
        }

        const int rbase = row0 + w * 16;
        if (jt * 64 + 63 <= rbase) {
            #pragma unroll
            for (int c = 0; c < 4; ++c)
                #pragma unroll
                for (int reg = 0; reg < 4; ++reg)
                    lsum[reg] += exp2f(sf[c][reg] * C2);
        } else {
            #pragma unroll
            for (int c = 0; c < 4; ++c) {
                const int jcol = jt * 64 + c * 16 + l15;
                #pragma unroll
                for (int reg = 0; reg < 4; ++reg) {
                    const int grow = rbase + l4 * 4 + reg;
                    lsum[reg] += (jcol <= grow) ? exp2f(sf[c][reg] * C2) : 0.f;
                }
            }
        }
    }

    float nl2[4];
    #pragma unroll
    for (int reg = 0; reg < 4; ++reg) {
        float s = lsum[reg];
        #pragma unroll
        for (int off = 1; off < 16; off <<= 1)
            s += __shfl_xor(s, off);
        nl2[reg] = -__log2f(s);
    }

    // ---- pass 2: P write + PV; K and V both gll16-staged ----
    floatx4 o[4] = {};

    __syncthreads();                      // pass-1 Ks reads done before restage
    #pragma unroll
    for (int i = 0; i < 2; ++i)
        gll16(kh + (size_t)(w * 16 + i * 8 + srow) * HD + sblk * 8,
              &Ks[(w * 16 + i * 8) * 64]);

    for (int jt = 0; jt < nt; ++jt) {
        const int buf = jt & 1;
        asm volatile("s_waitcnt vmcnt(0)" ::: "memory");   // K(jt) landed
        __syncthreads();                   // B: all PV(jt-1) done; K(jt) visible

        // stage V(jt) from transposed global (FIFO-older than K(jt+1))
        #pragma unroll
        for (int i = 0; i < 2; ++i)
            gll16(vth + (size_t)(w * 16 + i * 8 + srow) * S_LEN + jt * 64 + sblk * 8,
                  &Vt[(w * 16 + i * 8) * 64]);
        if (jt + 1 < nt) {
            #pragma unroll
            for (int i = 0; i < 2; ++i)
                gll16(kh + (size_t)((jt + 1) * 64 + w * 16 + i * 8 + srow) * HD + sblk * 8,
                      &Ks[(buf ^ 1) * 4096 + (w * 16 + i * 8) * 64]);
        }

        floatx4 sf[4] = {};
        #pragma unroll
        for (int ks = 0; ks < 2; ++ks) {
            short8 kb[4];
            #pragma unroll
            for (int c = 0; c < 4; ++c) {
                const int r = c * 16 + l15;
                kb[c] = *(const short8*)&Ks[buf * 4096 + r * 64
                                            + (((ks * 4 + l4) ^ (r & 7)) << 3)];
            }
            #pragma unroll
            for (int c = 0; c < 4; ++c)
                sf[c] = __builtin_amdgcn_mfma_f32_16x16x32_bf16(qa[ks], kb[c], sf[c], 0, 0, 0);
        }

        const int rbase = row0 + w * 16;
        const bool full = (jt * 64 + 63 <= rbase);
        #pragma unroll
        for (int c = 0; c < 4; ++c) {
            const int jcol = jt * 64 + c * 16 + l15;
            #pragma unroll
            for (int reg = 0; reg < 4; ++reg) {
                const int rl = w * 16 + l4 * 4 + reg;
                float p = exp2f(fmaf(sf[c][reg], C2, nl2[reg]));
                if (!full && jcol > rbase + l4 * 4 + reg) p = 0.f;
                Ps[rl * 88 + c * 16 + l15] = f2b(p);
            }
        }
        if (jt + 1 < nt) {
            asm volatile("s_waitcnt vmcnt(2)" ::: "memory");   // V(jt) landed
        } else {
            asm volatile("s_waitcnt vmcnt(0)" ::: "memory");
        }
        __syncthreads();                   // C: Ps + Vt ready

        // coalesced NONTEMPORAL attn tile write from Ps
        #pragma unroll
        for (int i2 = 0; i2 < 4; ++i2) {
            const int idx = tid + i2 * 256;
            const int r = idx >> 4, c4 = (idx & 15) * 4;
            const ushort4 pb = *(const ushort4*)&Ps[r * 88 + c4];
            floatx4 pf;
            pf[0] = b2f(pb.x); pf[1] = b2f(pb.y); pf[2] = b2f(pb.z); pf[3] = b2f(pb.w);
            __builtin_nontemporal_store(
                pf, (floatx4*)(attnh + (size_t)(row0 + r) * S_LEN + jt * 64 + c4));
        }

        // PV MFMA (vb read pattern identical to kb — conflict-free)
        #pragma unroll
        for (int ks = 0; ks < 2; ++ks) {
            const short8 pa = *(const short8*)&Ps[(w * 16 + l15) * 88 + ks * 32 + l4 * 8];
            #pragma unroll
            for (int c = 0; c < 4; ++c) {
                const int r = c * 16 + l15;
                const short8 vb = *(const short8*)&Vt[r * 64
                                                     + (((ks * 4 + l4) ^ (r & 7)) << 3)];
                o[c] = __builtin_amdgcn_mfma_f32_16x16x32_bf16(pa, vb, o[c], 0, 0, 0);
            }
        }
    }

    // context out (bf16, [B, S, H*64])
    const int b = bh >> 4, h = bh & 15;
    #pragma unroll
    for (int c = 0; c < 4; ++c)
        #pragma unroll
        for (int reg = 0; reg < 4; ++reg) {
            const int gr = row0 + w * 16 + l4 * 4 + reg;
            const int d = c * 16 + l15;
            ctx[((size_t)b * S_LEN + gr) * DMODEL + h * HD + d] = f2b(o[c][reg]);
        }

    // zero-fill strictly-above-diagonal tiles (nontemporal)
    const floatx4 z4 = {0.f, 0.f, 0.f, 0.f};
    for (int jt = nt; jt < S_LEN / 64; ++jt) {
        #pragma unroll
        for (int i = 0; i < 4; ++i) {
            const int idx = tid + i * 256;
            const int r = idx >> 4, off = (idx & 15) * 4;
            __builtin_nontemporal_store(
                z4, (floatx4*)(attnh + (size_t)(row0 + r) * S_LEN + jt * 64 + off));
        }
    }
}

// ---------------------------------------------------------------------------
extern "C" void kernel_launch(void* const* d_in, const int* in_sizes, int n_in,
                              void* d_out, int out_size, void* d_ws, size_t ws_size,
                              hipStream_t stream)
{
    const float* Q  = (const float*)d_in[0];
    const float* K  = (const float*)d_in[1];
    const float* V  = (const float*)d_in[2];
    const float* Wq = (const float*)d_in[4];
    const float* bq = (const float*)d_in[5];
    const float* Wk = (const float*)d_in[6];
    const float* bk = (const float*)d_in[7];
    const float* Wv = (const float*)d_in[8];
    const float* bv = (const float*)d_in[9];
    const float* Wo = (const float*)d_in[10];
    const float* bo = (const float*)d_in[11];

    float* out  = (float*)d_out;
    float* attn = out + (size_t)NBATCH * S_LEN * DMODEL;

    const size_t per = (size_t)NBATCH * S_LEN * DMODEL;
    const size_t wsz = (size_t)DMODEL * DMODEL;
    unsigned short* Xq  = (unsigned short*)d_ws;
    unsigned short* Xk  = Xq + per;
    unsigned short* Xv  = Xk + per;
    unsigned short* Wtq = Xv + per;
    unsigned short* Wtk = Wtq + wsz;
    unsigned short* Wtv = Wtk + wsz;
    unsigned short* Wto = Wtv + wsz;
    unsigned short* qhw = Wto + wsz;
    unsigned short* khw = qhw + per;
    unsigned short* vhw = khw + per;   // V transposed: [B,H,64,S]
    unsigned short* ctx = vhw + per;

    const int n4 = (int)(per / 4);
    convert_bf16<<<dim3((n4 + 255) / 256, 1, 3), 256, 0, stream>>>(
        Q, K, V, Xq, Xk, Xv, n4);
    transpose_w<<<dim3(16, 16, 4), 256, 0, stream>>>(Wq, Wk, Wv, Wo, Wtq, Wtk, Wtv, Wto);

    gemm_qkv<<<dim3(DMODEL / 128, (NBATCH * S_LEN) / 128, 3), 256, 0, stream>>>(
        Xq, Xk, Xv, Wtq, Wtk, Wtv, bq, bk, bv, qhw, khw, vhw);

    attn_mfma<<<1024, 256, 0, stream>>>(qhw, khw, vhw, attn, ctx);

    gemm_out<<<dim3(DMODEL / 64, (NBATCH * S_LEN) / 128), 256, 0, stream>>>(
        ctx, Wto, bo, out);
}